// Round 5
// baseline (251.528 us; speedup 1.0000x reference)
//
#include <hip/hip_runtime.h>
#include <hip/hip_bf16.h>

#define NN 50000
#define NE 800000
#define FIN 128
#define HD 64
#define NC 40
#define XG   782    // hist/init MFMA grid (NN/16/4 rounded up)
#define XG2  781    // xform0 blocks appended to k_ellx
#define NB   391    // edge chunks of 2048 edges (ceil(NE/2048))
#define NBK  782    // dst buckets of 64 nodes (ceil(NN/64))
#define BW   64     // bucket width (nodes per bucket)
#define BSTR 2048   // fixed packed-slots per bucket (max bucket ~1180 for this input)

typedef __hip_bfloat16 bf16;
typedef __attribute__((ext_vector_type(8))) short bf16x8;   // 8 bf16 in 4 VGPRs
typedef __attribute__((ext_vector_type(4))) float f32x4;

// accumulate 8 bf16 (one uint4) into fp32 bank
__device__ __forceinline__ void acc8(float* a, uint4 v){
  a[0] += __uint_as_float(v.x << 16); a[1] += __uint_as_float(v.x & 0xffff0000u);
  a[2] += __uint_as_float(v.y << 16); a[3] += __uint_as_float(v.y & 0xffff0000u);
  a[4] += __uint_as_float(v.z << 16); a[5] += __uint_as_float(v.z & 0xffff0000u);
  a[6] += __uint_as_float(v.w << 16); a[7] += __uint_as_float(v.w & 0xffff0000u);
}

__device__ __forceinline__ unsigned pack2(float lo, float hi){
  union { bf16 b; unsigned short u; } a, b;
  a.b = __float2bfloat16(lo);
  b.b = __float2bfloat16(hi);
  return (unsigned)a.u | ((unsigned)b.u << 16);
}

__device__ __forceinline__ short f2bf_bits(float f){
  union { bf16 b; short s; } u;
  u.b = __float2bfloat16(f);
  return u.s;
}

// MFMA h0/hyp init body (unchanged from prior best)
__device__ __forceinline__ void init_body(
    int wid, const float* __restrict__ x, const float* __restrict__ pos,
    const float* __restrict__ Wi, const float* __restrict__ bi,
    const float* __restrict__ Wp, const float* __restrict__ bp,
    bf16* __restrict__ h0b, bf16* __restrict__ hypb, int lane){
  const int quad = lane >> 4;
  const int col  = lane & 15;
  const int nw   = XG * 4;

  bf16x8 wif[4][4];
  #pragma unroll
  for (int ct = 0; ct < 4; ++ct)
    #pragma unroll
    for (int kf = 0; kf < 4; ++kf)
      #pragma unroll
      for (int j = 0; j < 8; ++j)
        wif[ct][kf][j] = f2bf_bits(Wi[(kf*32 + quad*8 + j)*HD + ct*16 + col]);
  bf16x8 wpf[4];
  #pragma unroll
  for (int ct = 0; ct < 4; ++ct)
    #pragma unroll
    for (int j = 0; j < 8; ++j){
      const int k = quad*8 + j;
      wpf[ct][j] = (k < 16) ? f2bf_bits(Wp[k*HD + ct*16 + col]) : (short)0;
    }
  float bih[4], bph[4];
  #pragma unroll
  for (int c = 0; c < 4; ++c){ bih[c] = bi[c*16 + col]; bph[c] = bp[c*16 + col]; }

  for (int t = wid; t < NN/16; t += nw){
    const int n0 = t * 16;
    bf16x8 af[4];
    #pragma unroll
    for (int kf = 0; kf < 4; ++kf){
      const float* xr = x + (size_t)(n0 + col)*FIN + kf*32 + quad*8;
      const float4 f0 = *(const float4*)xr;
      const float4 f1 = *(const float4*)(xr + 4);
      af[kf][0] = f2bf_bits(f0.x); af[kf][1] = f2bf_bits(f0.y);
      af[kf][2] = f2bf_bits(f0.z); af[kf][3] = f2bf_bits(f0.w);
      af[kf][4] = f2bf_bits(f1.x); af[kf][5] = f2bf_bits(f1.y);
      af[kf][6] = f2bf_bits(f1.z); af[kf][7] = f2bf_bits(f1.w);
    }
    bf16x8 ap;
    #pragma unroll
    for (int j = 0; j < 8; ++j) ap[j] = 0;
    if (quad < 2){
      const float* pr = pos + (size_t)(n0 + col)*16 + quad*8;
      const float4 p0 = *(const float4*)pr;
      const float4 p1 = *(const float4*)(pr + 4);
      ap[0] = f2bf_bits(p0.x); ap[1] = f2bf_bits(p0.y);
      ap[2] = f2bf_bits(p0.z); ap[3] = f2bf_bits(p0.w);
      ap[4] = f2bf_bits(p1.x); ap[5] = f2bf_bits(p1.y);
      ap[6] = f2bf_bits(p1.z); ap[7] = f2bf_bits(p1.w);
    }
    f32x4 ah[4], app[4];
    #pragma unroll
    for (int c = 0; c < 4; ++c){
      ah[c]  = (f32x4){bih[c], bih[c], bih[c], bih[c]};
      app[c] = (f32x4){bph[c], bph[c], bph[c], bph[c]};
    }
    #pragma unroll
    for (int ct = 0; ct < 4; ++ct){
      #pragma unroll
      for (int kf = 0; kf < 4; ++kf)
        ah[ct] = __builtin_amdgcn_mfma_f32_16x16x32_bf16(af[kf], wif[ct][kf], ah[ct], 0, 0, 0);
      app[ct] = __builtin_amdgcn_mfma_f32_16x16x32_bf16(ap, wpf[ct], app[ct], 0, 0, 0);
    }
    #pragma unroll
    for (int reg = 0; reg < 4; ++reg){
      const int n = n0 + quad*4 + reg;
      #pragma unroll
      for (int c = 0; c < 4; ++c){
        h0b[(size_t)n*HD + c*16 + col]  = __float2bfloat16(ah[c][reg]);
        hypb[(size_t)n*HD + c*16 + col] = __float2bfloat16(tanhf(app[c][reg]));
      }
    }
  }
}

// dense xform body: y = h@Wl ; z = h@Wr + b (+hyp)   (bf16 io, fp32 accum)
__device__ __forceinline__ void xform_body(
    int wid, int nw, const bf16* __restrict__ h, const float* __restrict__ Wl,
    const float* __restrict__ Wr, const float* __restrict__ bc,
    const bf16* __restrict__ hypb, const int use_hyp,
    bf16* __restrict__ y, bf16* __restrict__ z, int lane){
  const int quad = lane >> 4;
  const int col  = lane & 15;

  bf16x8 bfr[8][2];
  #pragma unroll
  for (int ct = 0; ct < 8; ++ct){
    const float* W = (ct < 4) ? Wl : Wr;
    const int nc = (ct & 3) * 16 + col;
    #pragma unroll
    for (int kf = 0; kf < 2; ++kf)
      #pragma unroll
      for (int j = 0; j < 8; ++j)
        bfr[ct][kf][j] = f2bf_bits(W[(kf*32 + quad*8 + j)*HD + nc]);
  }
  float zb[4];
  #pragma unroll
  for (int c = 0; c < 4; ++c) zb[c] = bc[c*16 + col];

  for (int t = wid; t < NN/16; t += nw){
    const int n0 = t * 16;
    union { uint4 u; bf16x8 v; } a0, a1;
    a0.u = *(const uint4*)(h + (size_t)(n0 + col)*HD + quad*8);
    a1.u = *(const uint4*)(h + (size_t)(n0 + col)*HD + 32 + quad*8);
    f32x4 acc[8];
    #pragma unroll
    for (int c = 0; c < 4; ++c) acc[c] = (f32x4){0.f, 0.f, 0.f, 0.f};
    #pragma unroll
    for (int c = 0; c < 4; ++c) acc[4+c] = (f32x4){zb[c], zb[c], zb[c], zb[c]};
    #pragma unroll
    for (int ct = 0; ct < 8; ++ct){
      acc[ct] = __builtin_amdgcn_mfma_f32_16x16x32_bf16(a0.v, bfr[ct][0], acc[ct], 0, 0, 0);
      acc[ct] = __builtin_amdgcn_mfma_f32_16x16x32_bf16(a1.v, bfr[ct][1], acc[ct], 0, 0, 0);
    }
    #pragma unroll
    for (int reg = 0; reg < 4; ++reg){
      const int n = n0 + quad*4 + reg;
      #pragma unroll
      for (int c = 0; c < 4; ++c){
        y[(size_t)n*HD + c*16 + col] = __float2bfloat16(acc[c][reg]);
        float zv = acc[4+c][reg];
        if (use_hyp) zv += __bfloat162float(hypb[(size_t)n*HD + c*16 + col]);
        z[(size_t)n*HD + c*16 + col] = __float2bfloat16(zv);
      }
    }
  }
}

// Pass 1: per-chunk LDS histogram over 782 coarse dst-buckets + MFMA init.
__global__ __launch_bounds__(256) void k_hist(
    const int* __restrict__ ei, int* __restrict__ histT,
    const float* __restrict__ x, const float* __restrict__ pos,
    const float* __restrict__ Wi, const float* __restrict__ bi,
    const float* __restrict__ Wp, const float* __restrict__ bp,
    bf16* __restrict__ h0b, bf16* __restrict__ hypb){
  __shared__ int lh[NBK];
  if (blockIdx.x < NB){
    for (int i = threadIdx.x; i < NBK; i += 256) lh[i] = 0;
    __syncthreads();
    int e = blockIdx.x * 2048 + threadIdx.x;
    #pragma unroll
    for (int j = 0; j < 8; ++j, e += 256)
      if (e < NE) atomicAdd(&lh[ei[NE + e] >> 6], 1);   // LDS atomic only
    __syncthreads();
    for (int i = threadIdx.x; i < NBK; i += 256)
      histT[blockIdx.x*NBK + i] = lh[i];                // coalesced dense store
    return;
  }
  init_body((blockIdx.x - NB) * 4 + (threadIdx.x >> 6),
            x, pos, Wi, bi, Wp, bp, h0b, hypb, threadIdx.x & 63);
}

// Pass 2: per bucket b: exclusive scan over the 391 chunk counts -> ofsT + total.
__global__ __launch_bounds__(512) void k_scanA(
    const int* __restrict__ histT, int* __restrict__ ofsT,
    int* __restrict__ totals){
  __shared__ int sc[512];
  const int b = blockIdx.x;
  const int t = threadIdx.x;
  const int v = (t < NB) ? histT[t*NBK + b] : 0;
  sc[t] = v; __syncthreads();
  for (int off = 1; off < 512; off <<= 1){
    const int xv = (t >= off) ? sc[t - off] : 0;
    __syncthreads();
    sc[t] += xv;
    __syncthreads();
  }
  if (t < NB) ofsT[t*NBK + b] = sc[t] - v;   // exclusive, relative to bucket base
  if (t == 511) totals[b] = sc[511];
}

// Pass 3: fixed-stride buckets (BSTR slots each) -> no cross-bucket scan needed.
__global__ __launch_bounds__(256) void k_scatter(
    const int* __restrict__ ei, const int* __restrict__ ofsT,
    int* __restrict__ packed){
  __shared__ int cur[NBK];
  for (int i = threadIdx.x; i < NBK; i += 256)
    cur[i] = (i << 11) + ofsT[blockIdx.x*NBK + i];
  __syncthreads();
  int e = blockIdx.x * 2048 + threadIdx.x;
  #pragma unroll
  for (int j = 0; j < 8; ++j, e += 256){
    if (e < NE){
      const int d = ei[NE + e];
      const int s = ei[e];                       // NN=50000 < 65536: fits 16 bits
      const int b = d >> 6;
      const int p = atomicAdd(&cur[b], 1);       // LDS atomic
      if (p < ((b + 1) << 11))                   // overflow guard (never for this input)
        packed[p] = s | ((d & 63) << 16);
    }
  }
}

// Pass 4: blocks [0,NBK): build 16-bit ELL rows with entries BUCKETED BY
// SRC-QUARTER (src>>14: 2MB y-window per quarter, fits one XCD's 4MB L2).
// Concurrent gather waves then sweep src-quarters roughly in phase ->
// repeat reads hit L2 instead of L3. Blocks [NBK,..): xform layer 0.
__global__ __launch_bounds__(256) void k_ellx(
    const int* __restrict__ packed, const int* __restrict__ totals,
    unsigned short* __restrict__ esrc, int* __restrict__ degp,
    const bf16* __restrict__ h0, const float* __restrict__ Wl,
    const float* __restrict__ Wr, const float* __restrict__ bc,
    const bf16* __restrict__ hypb, bf16* __restrict__ y, bf16* __restrict__ z){
  if (blockIdx.x < NBK){
    __shared__ int cnt4[BW*4];     // per-node per-src-quarter counts -> cursors
    __shared__ unsigned short ell[BW * 64];
    for (int i = threadIdx.x; i < BW*4; i += 256) cnt4[i] = 0;
    __syncthreads();
    const int b  = blockIdx.x;
    const int lo = b << 11;
    const int hi = lo + totals[b];
    // pass A: count per (node, src-quarter)
    for (int e = lo + threadIdx.x; e < hi; e += 256){
      const int pk = packed[e];
      const int dl = (pk >> 16) & 63;
      const int q  = (pk & 0xffff) >> 14;
      atomicAdd(&cnt4[dl*4 + q], 1);
    }
    __syncthreads();
    // per-node exclusive prefix over the 4 quarters; cnt4 becomes cursor base
    if (threadIdx.x < BW){
      const int i4 = threadIdx.x * 4;
      int s = 0;
      #pragma unroll
      for (int q = 0; q < 4; ++q){
        const int c = cnt4[i4 + q];
        cnt4[i4 + q] = s;
        s += c;
      }
      const int n = b*BW + threadIdx.x;
      if (n < NN) degp[n] = min(s, 64);
    }
    __syncthreads();
    // pass B: place src into quarter-sorted row position
    for (int e = lo + threadIdx.x; e < hi; e += 256){
      const int pk = packed[e];
      const int dl = (pk >> 16) & 63;
      const int sv = pk & 0xffff;
      const int p  = atomicAdd(&cnt4[dl*4 + (sv >> 14)], 1);
      if (p < 64) ell[dl*64 + p] = (unsigned short)sv;
    }
    __syncthreads();
    const int n0 = b * BW;
    for (int i = threadIdx.x; i < BW * 8; i += 256){
      const int node = i >> 3;
      if (n0 + node < NN)
        ((uint4*)(esrc + (size_t)(n0 + node)*64))[i & 7] = ((const uint4*)ell)[i];
    }
    return;
  }
  xform_body((blockIdx.x - NBK)*4 + (threadIdx.x >> 6), XG2*4,
             h0, Wl, Wr, bc, hypb, 1, y, z, threadIdx.x & 63);
}

// gather phase: 8 nodes/wave, 32 nodes/block; result staged to LDS as bf16
// rows (XOR-swizzled 16B slots to dodge the 128B-stride bank conflict).
__device__ __forceinline__ void gather_stage(
    const bf16* __restrict__ y, const bf16* __restrict__ z,
    const int* __restrict__ degp, const unsigned short* __restrict__ esrc,
    unsigned int* hs, const int do_relu){
  const int lane = threadIdx.x & 63;
  const int w    = threadIdx.x >> 6;
  const int grp  = lane >> 3;
  const int fq   = lane & 7;
  const int nl   = (w << 3) + grp;
  const int n    = (blockIdx.x << 5) + nl;
  const int ns   = (n < NN) ? n : 0;
  const int deg  = (n < NN) ? min(degp[n], 64) : 0;
  const uint4* er = (const uint4*)(esrc + ((size_t)ns << 6));
  float a[8] = {0,0,0,0,0,0,0,0};
  for (int eb = 0; eb < 64; eb += 8){
    if (!__any(eb < deg)) break;
    union { uint4 u; unsigned short s[8]; } ev;
    ev.u = er[eb >> 3];
    const int m = deg - eb;
    #pragma unroll
    for (int j = 0; j < 8; ++j){
      if (j < m){
        const uint4 v = ((const uint4*)(y + (size_t)ev.s[j]*HD))[fq];
        acc8(a, v);
      }
    }
  }
  const float inv = deg > 0 ? 1.f / (float)deg : 0.f;
  const uint4 zv = ((const uint4*)(z + (size_t)ns*HD))[fq];
  float zf[8];
  zf[0] = __uint_as_float(zv.x << 16); zf[1] = __uint_as_float(zv.x & 0xffff0000u);
  zf[2] = __uint_as_float(zv.y << 16); zf[3] = __uint_as_float(zv.y & 0xffff0000u);
  zf[4] = __uint_as_float(zv.z << 16); zf[5] = __uint_as_float(zv.z & 0xffff0000u);
  zf[6] = __uint_as_float(zv.w << 16); zf[7] = __uint_as_float(zv.w & 0xffff0000u);
  float o[8];
  #pragma unroll
  for (int j = 0; j < 8; ++j){
    o[j] = a[j]*inv + zf[j];
    if (do_relu) o[j] = fmaxf(o[j], 0.f);
  }
  uint4 pv;
  pv.x = pack2(o[0], o[1]);
  pv.y = pack2(o[2], o[3]);
  pv.z = pack2(o[4], o[5]);
  pv.w = pack2(o[6], o[7]);
  *(uint4*)(hs + nl*32 + ((fq ^ (nl & 7)) << 2)) = pv;
}

__device__ __forceinline__ bf16x8 lds_frag(const unsigned int* hs, int r, int slotlin){
  union { uint4 u; bf16x8 v; } t;
  t.u = *(const uint4*)(hs + r*32 + ((slotlin ^ (r & 7)) << 2));
  return t.v;
}

// Fused gather(l) [+relu,+already-z] -> xform(l+1): h_{l+1} never hits HBM.
__global__ __launch_bounds__(256) void k_gx(
    const bf16* __restrict__ y, const bf16* __restrict__ z,
    const int* __restrict__ degp, const unsigned short* __restrict__ esrc,
    const float* __restrict__ Wl, const float* __restrict__ Wr,
    const float* __restrict__ bc, const bf16* __restrict__ hypb,
    const int use_hyp, bf16* __restrict__ yo, bf16* __restrict__ zo){
  __shared__ unsigned int hs[32*32];     // 32 node-rows x 64 bf16, swizzled
  const int lane = threadIdx.x & 63;
  const int w    = threadIdx.x >> 6;
  const int quad = lane >> 4;
  const int col  = lane & 15;
  const int tile = w & 1;                // 16-node tile
  const int ch   = w >> 1;               // col half: ct in {2ch, 2ch+1}

  bf16x8 fl[2][2], fr[2][2];
  float zb[2];
  #pragma unroll
  for (int c = 0; c < 2; ++c){
    const int nc = (ch*2 + c)*16 + col;
    zb[c] = bc[nc];
    #pragma unroll
    for (int kf = 0; kf < 2; ++kf)
      #pragma unroll
      for (int j = 0; j < 8; ++j){
        fl[c][kf][j] = f2bf_bits(Wl[(kf*32 + quad*8 + j)*HD + nc]);
        fr[c][kf][j] = f2bf_bits(Wr[(kf*32 + quad*8 + j)*HD + nc]);
      }
  }

  gather_stage(y, z, degp, esrc, hs, 1);
  __syncthreads();

  const int r = tile*16 + col;
  const bf16x8 a0 = lds_frag(hs, r, quad);
  const bf16x8 a1 = lds_frag(hs, r, quad + 4);
  f32x4 ay[2], az[2];
  #pragma unroll
  for (int c = 0; c < 2; ++c){
    ay[c] = (f32x4){0.f, 0.f, 0.f, 0.f};
    az[c] = (f32x4){zb[c], zb[c], zb[c], zb[c]};
    ay[c] = __builtin_amdgcn_mfma_f32_16x16x32_bf16(a0, fl[c][0], ay[c], 0, 0, 0);
    ay[c] = __builtin_amdgcn_mfma_f32_16x16x32_bf16(a1, fl[c][1], ay[c], 0, 0, 0);
    az[c] = __builtin_amdgcn_mfma_f32_16x16x32_bf16(a0, fr[c][0], az[c], 0, 0, 0);
    az[c] = __builtin_amdgcn_mfma_f32_16x16x32_bf16(a1, fr[c][1], az[c], 0, 0, 0);
  }
  const int n0b = blockIdx.x << 5;
  #pragma unroll
  for (int reg = 0; reg < 4; ++reg){
    const int n = n0b + tile*16 + quad*4 + reg;
    if (n < NN){
      #pragma unroll
      for (int c = 0; c < 2; ++c){
        const int oc = (ch*2 + c)*16 + col;
        yo[(size_t)n*HD + oc] = __float2bfloat16(ay[c][reg]);
        float zv = az[c][reg];
        if (use_hyp) zv += __bfloat162float(hypb[(size_t)n*HD + oc]);
        zo[(size_t)n*HD + oc] = __float2bfloat16(zv);
      }
    }
  }
}

// Fused gather(2) [no relu] -> final matmul + log_softmax.
__global__ __launch_bounds__(256) void k_gf(
    const bf16* __restrict__ y, const bf16* __restrict__ z,
    const int* __restrict__ degp, const unsigned short* __restrict__ esrc,
    const float* __restrict__ Wl, const float* __restrict__ bl,
    float* __restrict__ out){
  __shared__ unsigned int hs[32*32];
  const int lane = threadIdx.x & 63;
  const int w    = threadIdx.x >> 6;
  const int quad = lane >> 4;
  const int col  = lane & 15;

  bf16x8 wf[3][2];
  float bb[3];
  #pragma unroll
  for (int ct = 0; ct < 3; ++ct){
    const int nc = ct*16 + col;
    const bool valid = nc < NC;
    bb[ct] = valid ? bl[nc] : -1e30f;
    #pragma unroll
    for (int kf = 0; kf < 2; ++kf)
      #pragma unroll
      for (int j = 0; j < 8; ++j)
        wf[ct][kf][j] = valid ? f2bf_bits(Wl[(kf*32 + quad*8 + j)*NC + nc]) : (short)0;
  }

  gather_stage(y, z, degp, esrc, hs, 0);
  __syncthreads();
  if (w >= 2) return;                    // waves 0,1 handle the 2 node-tiles

  const int tile = w;
  const int r = tile*16 + col;
  const bf16x8 a0 = lds_frag(hs, r, quad);
  const bf16x8 a1 = lds_frag(hs, r, quad + 4);
  f32x4 acc[3];
  #pragma unroll
  for (int ct = 0; ct < 3; ++ct){
    acc[ct] = (f32x4){bb[ct], bb[ct], bb[ct], bb[ct]};
    acc[ct] = __builtin_amdgcn_mfma_f32_16x16x32_bf16(a0, wf[ct][0], acc[ct], 0, 0, 0);
    acc[ct] = __builtin_amdgcn_mfma_f32_16x16x32_bf16(a1, wf[ct][1], acc[ct], 0, 0, 0);
  }
  const int n0b = blockIdx.x << 5;
  #pragma unroll
  for (int reg = 0; reg < 4; ++reg){
    const float e0 = acc[0][reg], e1 = acc[1][reg], e2 = acc[2][reg];
    float vmax = fmaxf(fmaxf(e0, e1), e2);
    vmax = fmaxf(vmax, __shfl_xor(vmax, 1, 64));
    vmax = fmaxf(vmax, __shfl_xor(vmax, 2, 64));
    vmax = fmaxf(vmax, __shfl_xor(vmax, 4, 64));
    vmax = fmaxf(vmax, __shfl_xor(vmax, 8, 64));
    float s = __expf(e0 - vmax) + __expf(e1 - vmax) + __expf(e2 - vmax);
    s += __shfl_xor(s, 1, 64);
    s += __shfl_xor(s, 2, 64);
    s += __shfl_xor(s, 4, 64);
    s += __shfl_xor(s, 8, 64);
    const float off = vmax + __logf(s);
    const int n = n0b + tile*16 + quad*4 + reg;
    if (n < NN){
      #pragma unroll
      for (int ct = 0; ct < 3; ++ct){
        const int nc = ct*16 + col;
        if (nc < NC){
          const float e = acc[ct][reg];
          out[(size_t)n*NC + nc]                 = e;
          out[(size_t)NN*NC + (size_t)n*NC + nc] = e - off;
        }
      }
    }
  }
}

extern "C" void kernel_launch(void* const* d_in, const int* in_sizes, int n_in,
                              void* d_out, int out_size, void* d_ws, size_t ws_size,
                              hipStream_t stream){
  (void)in_sizes; (void)n_in; (void)out_size; (void)ws_size;
  const float* x_h    = (const float*)d_in[0];
  const float* pos    = (const float*)d_in[1];
  const int*   ei     = (const int*)  d_in[2];
  const float* W_pos  = (const float*)d_in[3];
  const float* b_pos  = (const float*)d_in[4];
  const float* W_init = (const float*)d_in[5];
  const float* b_init = (const float*)d_in[6];
  const float* W_l    = (const float*)d_in[7];
  const float* W_r    = (const float*)d_in[8];
  const float* b_conv = (const float*)d_in[9];
  const float* W_last = (const float*)d_in[10];
  const float* b_last = (const float*)d_in[11];
  float* out = (float*)d_out;

  char* p = (char*)d_ws;
  auto alloc = [&](size_t bytes)->char*{
    char* r = p; p += (bytes + 255) & ~(size_t)255; return r;
  };
  bf16* hb0  = (bf16*)alloc((size_t)NN*HD*2);
  bf16* y0   = (bf16*)alloc((size_t)NN*HD*2);
  bf16* z0   = (bf16*)alloc((size_t)NN*HD*2);
  bf16* y1   = (bf16*)alloc((size_t)NN*HD*2);
  bf16* z1   = (bf16*)alloc((size_t)NN*HD*2);
  bf16* hypb = (bf16*)alloc((size_t)NN*HD*2);
  unsigned short* esrc = (unsigned short*)alloc((size_t)NN*64*2); // 16-bit ELL
  int* degp   = (int*)alloc((size_t)NN*4);
  int* histT  = (int*)alloc((size_t)NB*NBK*4);
  int* ofsT   = (int*)alloc((size_t)NB*NBK*4);
  int* totals = (int*)alloc((size_t)NBK*4);
  int* packed = (int*)alloc((size_t)NBK*BSTR*4);   // fixed-stride buckets, 6.4 MB

  // atomic-free counting sort (+init / +xform0 riding along), then fused layers
  k_hist   <<<NB + XG, 256, 0, stream>>>(ei, histT, x_h, pos,
                                         W_init, b_init, W_pos, b_pos, hb0, hypb);
  k_scanA  <<<NBK, 512, 0, stream>>>(histT, ofsT, totals);
  k_scatter<<<NB, 256, 0, stream>>>(ei, ofsT, packed);
  k_ellx   <<<NBK + XG2, 256, 0, stream>>>(packed, totals, esrc, degp,
                                           hb0, W_l, W_r, b_conv, hypb, y0, z0);
  // gather0 + xform1  (h1 stays on-chip)
  k_gx <<<1563, 256, 0, stream>>>(y0, z0, degp, esrc,
                                  W_l + 1*HD*HD, W_r + 1*HD*HD, b_conv + 1*HD,
                                  hypb, 1, y1, z1);
  // gather1 + xform2  (h2 stays on-chip; z2 without hyp)
  k_gx <<<1563, 256, 0, stream>>>(y1, z1, degp, esrc,
                                  W_l + 2*HD*HD, W_r + 2*HD*HD, b_conv + 2*HD,
                                  hypb, 0, y0, z0);
  // gather2 + final matmul + log_softmax
  k_gf <<<1563, 256, 0, stream>>>(y0, z0, degp, esrc, W_last, b_last, out);
}

// Round 6
// 240.699 us; speedup vs baseline: 1.0450x; 1.0450x over previous
//
#include <hip/hip_runtime.h>
#include <hip/hip_bf16.h>

#define NN 50000
#define NE 800000
#define FIN 128
#define HD 64
#define NC 40
#define XG   782    // hist/init MFMA grid (NN/16/4 rounded up)
#define NB   391    // edge chunks of 2048 edges (ceil(NE/2048))
#define NBK  782    // dst buckets of 64 nodes (ceil(NN/64))
#define BW   64     // bucket width (nodes per bucket)
#define BSTR 2048   // fixed packed-slots per bucket (max bucket ~1180 for this input)
#define GGRID 1563  // ceil(NN/32) blocks for the fused layer kernels

typedef __hip_bfloat16 bf16;
typedef __attribute__((ext_vector_type(8))) short bf16x8;   // 8 bf16 in 4 VGPRs
typedef __attribute__((ext_vector_type(4))) float f32x4;

// accumulate 8 bf16 (one uint4) into fp32 bank
__device__ __forceinline__ void acc8(float* a, uint4 v){
  a[0] += __uint_as_float(v.x << 16); a[1] += __uint_as_float(v.x & 0xffff0000u);
  a[2] += __uint_as_float(v.y << 16); a[3] += __uint_as_float(v.y & 0xffff0000u);
  a[4] += __uint_as_float(v.z << 16); a[5] += __uint_as_float(v.z & 0xffff0000u);
  a[6] += __uint_as_float(v.w << 16); a[7] += __uint_as_float(v.w & 0xffff0000u);
}

__device__ __forceinline__ unsigned pack2(float lo, float hi){
  union { bf16 b; unsigned short u; } a, b;
  a.b = __float2bfloat16(lo);
  b.b = __float2bfloat16(hi);
  return (unsigned)a.u | ((unsigned)b.u << 16);
}

__device__ __forceinline__ short f2bf_bits(float f){
  union { bf16 b; short s; } u;
  u.b = __float2bfloat16(f);
  return u.s;
}

// MFMA h0/hyp init body (unchanged from prior best)
__device__ __forceinline__ void init_body(
    int wid, const float* __restrict__ x, const float* __restrict__ pos,
    const float* __restrict__ Wi, const float* __restrict__ bi,
    const float* __restrict__ Wp, const float* __restrict__ bp,
    bf16* __restrict__ h0b, bf16* __restrict__ hypb, int lane){
  const int quad = lane >> 4;
  const int col  = lane & 15;
  const int nw   = XG * 4;

  bf16x8 wif[4][4];
  #pragma unroll
  for (int ct = 0; ct < 4; ++ct)
    #pragma unroll
    for (int kf = 0; kf < 4; ++kf)
      #pragma unroll
      for (int j = 0; j < 8; ++j)
        wif[ct][kf][j] = f2bf_bits(Wi[(kf*32 + quad*8 + j)*HD + ct*16 + col]);
  bf16x8 wpf[4];
  #pragma unroll
  for (int ct = 0; ct < 4; ++ct)
    #pragma unroll
    for (int j = 0; j < 8; ++j){
      const int k = quad*8 + j;
      wpf[ct][j] = (k < 16) ? f2bf_bits(Wp[k*HD + ct*16 + col]) : (short)0;
    }
  float bih[4], bph[4];
  #pragma unroll
  for (int c = 0; c < 4; ++c){ bih[c] = bi[c*16 + col]; bph[c] = bp[c*16 + col]; }

  for (int t = wid; t < NN/16; t += nw){
    const int n0 = t * 16;
    bf16x8 af[4];
    #pragma unroll
    for (int kf = 0; kf < 4; ++kf){
      const float* xr = x + (size_t)(n0 + col)*FIN + kf*32 + quad*8;
      const float4 f0 = *(const float4*)xr;
      const float4 f1 = *(const float4*)(xr + 4);
      af[kf][0] = f2bf_bits(f0.x); af[kf][1] = f2bf_bits(f0.y);
      af[kf][2] = f2bf_bits(f0.z); af[kf][3] = f2bf_bits(f0.w);
      af[kf][4] = f2bf_bits(f1.x); af[kf][5] = f2bf_bits(f1.y);
      af[kf][6] = f2bf_bits(f1.z); af[kf][7] = f2bf_bits(f1.w);
    }
    bf16x8 ap;
    #pragma unroll
    for (int j = 0; j < 8; ++j) ap[j] = 0;
    if (quad < 2){
      const float* pr = pos + (size_t)(n0 + col)*16 + quad*8;
      const float4 p0 = *(const float4*)pr;
      const float4 p1 = *(const float4*)(pr + 4);
      ap[0] = f2bf_bits(p0.x); ap[1] = f2bf_bits(p0.y);
      ap[2] = f2bf_bits(p0.z); ap[3] = f2bf_bits(p0.w);
      ap[4] = f2bf_bits(p1.x); ap[5] = f2bf_bits(p1.y);
      ap[6] = f2bf_bits(p1.z); ap[7] = f2bf_bits(p1.w);
    }
    f32x4 ah[4], app[4];
    #pragma unroll
    for (int c = 0; c < 4; ++c){
      ah[c]  = (f32x4){bih[c], bih[c], bih[c], bih[c]};
      app[c] = (f32x4){bph[c], bph[c], bph[c], bph[c]};
    }
    #pragma unroll
    for (int ct = 0; ct < 4; ++ct){
      #pragma unroll
      for (int kf = 0; kf < 4; ++kf)
        ah[ct] = __builtin_amdgcn_mfma_f32_16x16x32_bf16(af[kf], wif[ct][kf], ah[ct], 0, 0, 0);
      app[ct] = __builtin_amdgcn_mfma_f32_16x16x32_bf16(ap, wpf[ct], app[ct], 0, 0, 0);
    }
    #pragma unroll
    for (int reg = 0; reg < 4; ++reg){
      const int n = n0 + quad*4 + reg;
      #pragma unroll
      for (int c = 0; c < 4; ++c){
        h0b[(size_t)n*HD + c*16 + col]  = __float2bfloat16(ah[c][reg]);
        hypb[(size_t)n*HD + c*16 + col] = __float2bfloat16(tanhf(app[c][reg]));
      }
    }
  }
}

// Pass 1: per-chunk LDS histogram over 782 coarse dst-buckets + MFMA init.
__global__ __launch_bounds__(256) void k_hist(
    const int* __restrict__ ei, int* __restrict__ histT,
    const float* __restrict__ x, const float* __restrict__ pos,
    const float* __restrict__ Wi, const float* __restrict__ bi,
    const float* __restrict__ Wp, const float* __restrict__ bp,
    bf16* __restrict__ h0b, bf16* __restrict__ hypb){
  __shared__ int lh[NBK];
  if (blockIdx.x < NB){
    for (int i = threadIdx.x; i < NBK; i += 256) lh[i] = 0;
    __syncthreads();
    int e = blockIdx.x * 2048 + threadIdx.x;
    #pragma unroll
    for (int j = 0; j < 8; ++j, e += 256)
      if (e < NE) atomicAdd(&lh[ei[NE + e] >> 6], 1);   // LDS atomic only
    __syncthreads();
    for (int i = threadIdx.x; i < NBK; i += 256)
      histT[blockIdx.x*NBK + i] = lh[i];                // coalesced dense store
    return;
  }
  init_body((blockIdx.x - NB) * 4 + (threadIdx.x >> 6),
            x, pos, Wi, bi, Wp, bp, h0b, hypb, threadIdx.x & 63);
}

// Pass 2: per bucket b: exclusive scan over the 391 chunk counts -> ofsT + total.
__global__ __launch_bounds__(512) void k_scanA(
    const int* __restrict__ histT, int* __restrict__ ofsT,
    int* __restrict__ totals){
  __shared__ int sc[512];
  const int b = blockIdx.x;
  const int t = threadIdx.x;
  const int v = (t < NB) ? histT[t*NBK + b] : 0;
  sc[t] = v; __syncthreads();
  for (int off = 1; off < 512; off <<= 1){
    const int xv = (t >= off) ? sc[t - off] : 0;
    __syncthreads();
    sc[t] += xv;
    __syncthreads();
  }
  if (t < NB) ofsT[t*NBK + b] = sc[t] - v;   // exclusive, relative to bucket base
  if (t == 511) totals[b] = sc[511];
}

// Pass 3: fixed-stride buckets (BSTR slots each) -> no cross-bucket scan needed.
__global__ __launch_bounds__(256) void k_scatter(
    const int* __restrict__ ei, const int* __restrict__ ofsT,
    int* __restrict__ packed){
  __shared__ int cur[NBK];
  for (int i = threadIdx.x; i < NBK; i += 256)
    cur[i] = (i << 11) + ofsT[blockIdx.x*NBK + i];
  __syncthreads();
  int e = blockIdx.x * 2048 + threadIdx.x;
  #pragma unroll
  for (int j = 0; j < 8; ++j, e += 256){
    if (e < NE){
      const int d = ei[NE + e];
      const int s = ei[e];                       // NN=50000 < 65536: fits 16 bits
      const int b = d >> 6;
      const int p = atomicAdd(&cur[b], 1);       // LDS atomic
      if (p < ((b + 1) << 11))                   // overflow guard (never for this input)
        packed[p] = s | ((d & 63) << 16);
    }
  }
}

// Pass 4: one block per bucket: build 16-bit ELL rows (arrival order; quarter
// sort reverted - proven null) + deg array. Full-line esrc writes.
__global__ __launch_bounds__(256) void k_ell(
    const int* __restrict__ packed, const int* __restrict__ totals,
    unsigned short* __restrict__ esrc, int* __restrict__ degp){
  __shared__ int cnt[BW];
  __shared__ unsigned short ell[BW * 64];
  if (threadIdx.x < BW) cnt[threadIdx.x] = 0;
  __syncthreads();
  const int b  = blockIdx.x;
  const int lo = b << 11;
  const int hi = lo + totals[b];
  for (int e = lo + threadIdx.x; e < hi; e += 256){
    const int pk = packed[e];
    const int dl = (pk >> 16) & 63;
    const int p  = atomicAdd(&cnt[dl], 1);       // LDS atomic
    if (p < 64) ell[dl*64 + p] = (unsigned short)(pk & 0xffff);
  }
  __syncthreads();
  const int n0 = b * BW;
  for (int i = threadIdx.x; i < BW * 8; i += 256){
    const int node = i >> 3;
    if (n0 + node < NN)
      ((uint4*)(esrc + (size_t)(n0 + node)*64))[i & 7] = ((const uint4*)ell)[i];
  }
  for (int i = threadIdx.x; i < BW; i += 256)
    if (n0 + i < NN) degp[n0 + i] = min(cnt[i], 64);
}

// --- fused layer machinery -------------------------------------------------
// LDS convention: element (row r, col oc) of a 32x64 bf16 tile lives at byte
// r*128 + ((oc>>3)^(r&7))*16 + (oc&7)*2  (16B-slot XOR swizzle).

__device__ __forceinline__ bf16x8 lds_frag(const unsigned int* hs, int r, int slot){
  union { uint4 u; bf16x8 v; } t;
  t.u = *(const uint4*)(hs + r*32 + ((slot ^ (r & 7)) << 2));
  return t.v;
}

// gather mean of neighbor h rows -> hs[0..1023]; own h row -> hs[1024..2047]
__device__ __forceinline__ void gather_own_stage(
    const bf16* __restrict__ h, const int* __restrict__ degp,
    const unsigned short* __restrict__ esrc, unsigned int* hs){
  const int lane = threadIdx.x & 63;
  const int w    = threadIdx.x >> 6;
  const int grp  = lane >> 3;
  const int fq   = lane & 7;
  const int nl   = (w << 3) + grp;
  const int n    = (blockIdx.x << 5) + nl;
  const int ns   = (n < NN) ? n : 0;
  const int deg  = (n < NN) ? min(degp[n], 64) : 0;

  const uint4 hv = ((const uint4*)(h + (size_t)ns*HD))[fq];      // own row
  *(uint4*)(hs + 1024 + nl*32 + ((fq ^ (nl & 7)) << 2)) = hv;

  const uint4* er = (const uint4*)(esrc + ((size_t)ns << 6));
  float a[8] = {0,0,0,0,0,0,0,0};
  for (int eb = 0; eb < 64; eb += 8){
    if (!__any(eb < deg)) break;
    union { uint4 u; unsigned short s[8]; } ev;
    ev.u = er[eb >> 3];
    const int m = deg - eb;
    #pragma unroll
    for (int j = 0; j < 8; ++j){
      if (j < m){
        const uint4 v = ((const uint4*)(h + (size_t)ev.s[j]*HD))[fq];
        acc8(a, v);
      }
    }
  }
  const float inv = deg > 0 ? 1.f / (float)deg : 0.f;
  uint4 pv;
  pv.x = pack2(a[0]*inv, a[1]*inv);
  pv.y = pack2(a[2]*inv, a[3]*inv);
  pv.z = pack2(a[4]*inv, a[5]*inv);
  pv.w = pack2(a[6]*inv, a[7]*inv);
  *(uint4*)(hs + nl*32 + ((fq ^ (nl & 7)) << 2)) = pv;
}

// Layer kernel (l = 0,1): h_out = relu([mean_nbr(h) | h] @ [Wl;Wr] + b + hyp)
__global__ __launch_bounds__(256) void k_g(
    const bf16* __restrict__ h, const int* __restrict__ degp,
    const unsigned short* __restrict__ esrc,
    const float* __restrict__ Wl, const float* __restrict__ Wr,
    const float* __restrict__ bc, const bf16* __restrict__ hypb,
    bf16* __restrict__ ho){
  __shared__ unsigned int hs[2048];      // [0]:agg [1024]:own; reused for output
  const int lane = threadIdx.x & 63;
  const int w    = threadIdx.x >> 6;
  const int quad = lane >> 4;
  const int col  = lane & 15;
  const int tile = w & 1;                // 16-node tile
  const int ch   = w >> 1;               // 32-col half

  bf16x8 fw[2][4];                       // [Wl;Wr] stacked, K=128
  float zb[2];
  #pragma unroll
  for (int c = 0; c < 2; ++c){
    const int nc = (ch*2 + c)*16 + col;
    zb[c] = bc[nc];
    #pragma unroll
    for (int kf = 0; kf < 4; ++kf)
      #pragma unroll
      for (int j = 0; j < 8; ++j){
        const int k = kf*32 + quad*8 + j;
        fw[c][kf][j] = f2bf_bits((k < 64) ? Wl[k*HD + nc] : Wr[(k - 64)*HD + nc]);
      }
  }

  gather_own_stage(h, degp, esrc, hs);
  __syncthreads();

  const int r = tile*16 + col;
  const bf16x8 a0 = lds_frag(hs, r, quad);
  const bf16x8 a1 = lds_frag(hs, r, quad + 4);
  const bf16x8 a2 = lds_frag(hs + 1024, r, quad);
  const bf16x8 a3 = lds_frag(hs + 1024, r, quad + 4);
  __syncthreads();                       // frags in regs; hs free for output

  const int n0b = blockIdx.x << 5;
  unsigned short* st = (unsigned short*)hs;
  f32x4 acc[2];
  #pragma unroll
  for (int c = 0; c < 2; ++c){
    acc[c] = (f32x4){zb[c], zb[c], zb[c], zb[c]};
    acc[c] = __builtin_amdgcn_mfma_f32_16x16x32_bf16(a0, fw[c][0], acc[c], 0, 0, 0);
    acc[c] = __builtin_amdgcn_mfma_f32_16x16x32_bf16(a1, fw[c][1], acc[c], 0, 0, 0);
    acc[c] = __builtin_amdgcn_mfma_f32_16x16x32_bf16(a2, fw[c][2], acc[c], 0, 0, 0);
    acc[c] = __builtin_amdgcn_mfma_f32_16x16x32_bf16(a3, fw[c][3], acc[c], 0, 0, 0);
  }
  #pragma unroll
  for (int reg = 0; reg < 4; ++reg){
    const int rr = tile*16 + quad*4 + reg;
    const int nn = n0b + rr;
    #pragma unroll
    for (int c = 0; c < 2; ++c){
      const int oc = (ch*2 + c)*16 + col;
      float v = acc[c][reg];
      if (nn < NN) v += __bfloat162float(hypb[(size_t)nn*HD + oc]);
      v = fmaxf(v, 0.f);
      st[rr*64 + (((oc >> 3) ^ (rr & 7)) << 3) + (oc & 7)] = (unsigned short)f2bf_bits(v);
    }
  }
  __syncthreads();
  const int grp = lane >> 3;
  const int fq  = lane & 7;
  const int nl  = (w << 3) + grp;
  const int n   = n0b + nl;
  if (n < NN)                            // full-line coalesced h write
    ((uint4*)(ho + (size_t)n*HD))[fq] = *(const uint4*)(hs + nl*32 + ((fq ^ (nl & 7)) << 2));
}

// Layer 2 + final: h3 = [mean_nbr(h2)|h2]@[Wl;Wr]+b (no hyp/relu), then
// emb = h3@W_last + b_last ; out = [emb ; log_softmax(emb)]. h3 never hits HBM.
__global__ __launch_bounds__(256) void k_gf(
    const bf16* __restrict__ h, const int* __restrict__ degp,
    const unsigned short* __restrict__ esrc,
    const float* __restrict__ Wl, const float* __restrict__ Wr,
    const float* __restrict__ bc,
    const float* __restrict__ Wlast, const float* __restrict__ blast,
    float* __restrict__ out){
  __shared__ unsigned int hs[2048];
  const int lane = threadIdx.x & 63;
  const int w    = threadIdx.x >> 6;
  const int quad = lane >> 4;
  const int col  = lane & 15;
  const int tile = w & 1;
  const int ch   = w >> 1;

  bf16x8 fw[2][4];
  float zb[2];
  #pragma unroll
  for (int c = 0; c < 2; ++c){
    const int nc = (ch*2 + c)*16 + col;
    zb[c] = bc[nc];
    #pragma unroll
    for (int kf = 0; kf < 4; ++kf)
      #pragma unroll
      for (int j = 0; j < 8; ++j){
        const int k = kf*32 + quad*8 + j;
        fw[c][kf][j] = f2bf_bits((k < 64) ? Wl[k*HD + nc] : Wr[(k - 64)*HD + nc]);
      }
  }

  gather_own_stage(h, degp, esrc, hs);
  __syncthreads();

  const int r = tile*16 + col;
  const bf16x8 a0 = lds_frag(hs, r, quad);
  const bf16x8 a1 = lds_frag(hs, r, quad + 4);
  const bf16x8 a2 = lds_frag(hs + 1024, r, quad);
  const bf16x8 a3 = lds_frag(hs + 1024, r, quad + 4);
  __syncthreads();

  const int n0b = blockIdx.x << 5;
  unsigned short* st = (unsigned short*)hs;
  f32x4 acc[2];
  #pragma unroll
  for (int c = 0; c < 2; ++c){
    acc[c] = (f32x4){zb[c], zb[c], zb[c], zb[c]};
    acc[c] = __builtin_amdgcn_mfma_f32_16x16x32_bf16(a0, fw[c][0], acc[c], 0, 0, 0);
    acc[c] = __builtin_amdgcn_mfma_f32_16x16x32_bf16(a1, fw[c][1], acc[c], 0, 0, 0);
    acc[c] = __builtin_amdgcn_mfma_f32_16x16x32_bf16(a2, fw[c][2], acc[c], 0, 0, 0);
    acc[c] = __builtin_amdgcn_mfma_f32_16x16x32_bf16(a3, fw[c][3], acc[c], 0, 0, 0);
  }
  #pragma unroll
  for (int reg = 0; reg < 4; ++reg){
    const int rr = tile*16 + quad*4 + reg;
    #pragma unroll
    for (int c = 0; c < 2; ++c){
      const int oc = (ch*2 + c)*16 + col;
      st[rr*64 + (((oc >> 3) ^ (rr & 7)) << 3) + (oc & 7)] =
          (unsigned short)f2bf_bits(acc[c][reg]);
    }
  }
  __syncthreads();
  if (w >= 2) return;                    // waves 0,1: final matmul + softmax

  bf16x8 wf[3][2];
  float bb[3];
  #pragma unroll
  for (int ct = 0; ct < 3; ++ct){
    const int nc = ct*16 + col;
    const bool valid = nc < NC;
    bb[ct] = valid ? blast[nc] : -1e30f;
    #pragma unroll
    for (int kf = 0; kf < 2; ++kf)
      #pragma unroll
      for (int j = 0; j < 8; ++j)
        wf[ct][kf][j] = valid ? f2bf_bits(Wlast[(kf*32 + quad*8 + j)*NC + nc]) : (short)0;
  }
  const int r2 = w*16 + col;
  const bf16x8 b0 = lds_frag(hs, r2, quad);
  const bf16x8 b1 = lds_frag(hs, r2, quad + 4);
  f32x4 ac[3];
  #pragma unroll
  for (int ct = 0; ct < 3; ++ct){
    ac[ct] = (f32x4){bb[ct], bb[ct], bb[ct], bb[ct]};
    ac[ct] = __builtin_amdgcn_mfma_f32_16x16x32_bf16(b0, wf[ct][0], ac[ct], 0, 0, 0);
    ac[ct] = __builtin_amdgcn_mfma_f32_16x16x32_bf16(b1, wf[ct][1], ac[ct], 0, 0, 0);
  }
  #pragma unroll
  for (int reg = 0; reg < 4; ++reg){
    const float e0 = ac[0][reg], e1 = ac[1][reg], e2 = ac[2][reg];
    float vmax = fmaxf(fmaxf(e0, e1), e2);
    vmax = fmaxf(vmax, __shfl_xor(vmax, 1, 64));
    vmax = fmaxf(vmax, __shfl_xor(vmax, 2, 64));
    vmax = fmaxf(vmax, __shfl_xor(vmax, 4, 64));
    vmax = fmaxf(vmax, __shfl_xor(vmax, 8, 64));
    float s = __expf(e0 - vmax) + __expf(e1 - vmax) + __expf(e2 - vmax);
    s += __shfl_xor(s, 1, 64);
    s += __shfl_xor(s, 2, 64);
    s += __shfl_xor(s, 4, 64);
    s += __shfl_xor(s, 8, 64);
    const float off = vmax + __logf(s);
    const int n = n0b + w*16 + quad*4 + reg;
    if (n < NN){
      #pragma unroll
      for (int ct = 0; ct < 3; ++ct){
        const int nc = ct*16 + col;
        if (nc < NC){
          const float e = ac[ct][reg];
          out[(size_t)n*NC + nc]                 = e;
          out[(size_t)NN*NC + (size_t)n*NC + nc] = e - off;
        }
      }
    }
  }
}

extern "C" void kernel_launch(void* const* d_in, const int* in_sizes, int n_in,
                              void* d_out, int out_size, void* d_ws, size_t ws_size,
                              hipStream_t stream){
  (void)in_sizes; (void)n_in; (void)out_size; (void)ws_size;
  const float* x_h    = (const float*)d_in[0];
  const float* pos    = (const float*)d_in[1];
  const int*   ei     = (const int*)  d_in[2];
  const float* W_pos  = (const float*)d_in[3];
  const float* b_pos  = (const float*)d_in[4];
  const float* W_init = (const float*)d_in[5];
  const float* b_init = (const float*)d_in[6];
  const float* W_l    = (const float*)d_in[7];
  const float* W_r    = (const float*)d_in[8];
  const float* b_conv = (const float*)d_in[9];
  const float* W_last = (const float*)d_in[10];
  const float* b_last = (const float*)d_in[11];
  float* out = (float*)d_out;

  char* p = (char*)d_ws;
  auto alloc = [&](size_t bytes)->char*{
    char* r = p; p += (bytes + 255) & ~(size_t)255; return r;
  };
  bf16* buf0 = (bf16*)alloc((size_t)NN*HD*2);      // h0 / h2
  bf16* buf1 = (bf16*)alloc((size_t)NN*HD*2);      // h1
  bf16* hypb = (bf16*)alloc((size_t)NN*HD*2);
  unsigned short* esrc = (unsigned short*)alloc((size_t)NN*64*2); // 16-bit ELL
  int* degp   = (int*)alloc((size_t)NN*4);
  int* histT  = (int*)alloc((size_t)NB*NBK*4);
  int* ofsT   = (int*)alloc((size_t)NB*NBK*4);
  int* totals = (int*)alloc((size_t)NBK*4);
  int* packed = (int*)alloc((size_t)NBK*BSTR*4);   // fixed-stride buckets

  // atomic-free counting sort (+h0/hyp init riding along)
  k_hist   <<<NB + XG, 256, 0, stream>>>(ei, histT, x_h, pos,
                                         W_init, b_init, W_pos, b_pos, buf0, hypb);
  k_scanA  <<<NBK, 512, 0, stream>>>(histT, ofsT, totals);
  k_scatter<<<NB, 256, 0, stream>>>(ei, ofsT, packed);
  k_ell    <<<NBK, 256, 0, stream>>>(packed, totals, esrc, degp);

  // fused layers: gather(h) -> [agg|h] @ [Wl;Wr] (K=128) -> h_{l+1}
  k_g  <<<GGRID, 256, 0, stream>>>(buf0, degp, esrc,
                                   W_l + 0*HD*HD, W_r + 0*HD*HD, b_conv + 0*HD,
                                   hypb, buf1);
  k_g  <<<GGRID, 256, 0, stream>>>(buf1, degp, esrc,
                                   W_l + 1*HD*HD, W_r + 1*HD*HD, b_conv + 1*HD,
                                   hypb, buf0);
  k_gf <<<GGRID, 256, 0, stream>>>(buf0, degp, esrc,
                                   W_l + 2*HD*HD, W_r + 2*HD*HD, b_conv + 2*HD,
                                   W_last, b_last, out);
}